// Round 10
// baseline (398.248 us; speedup 1.0000x reference)
//
#include <hip/hip_runtime.h>
#include <hip/hip_bf16.h>
#include <stdint.h>

#define N_NODES 20000
#define MPAD    20096               // 157 * 128 padded rows for MFMA panels
#define N_EDG   320000
#define ET      (N_EDG + N_NODES)   // 340000
#define NFE     256
#define HD      512
#define NH      8
#define DH      64
#define NC      16

typedef __attribute__((ext_vector_type(8))) short short8;
typedef __attribute__((ext_vector_type(8))) _Float16 half8;
typedef __attribute__((ext_vector_type(4))) float f32x4;

#define AS1 __attribute__((address_space(1)))
#define AS3 __attribute__((address_space(3)))

__device__ __forceinline__ unsigned short f2bf(float f) {
    unsigned u = __float_as_uint(f);
    return (unsigned short)((u + 0x7FFFu + ((u >> 16) & 1u)) >> 16);
}
__device__ __forceinline__ float bf2f(unsigned short s) {
    return __uint_as_float(((unsigned)s) << 16);
}

// ---------------- CSR build ----------------
__global__ void count_deg(const int* __restrict__ ei, int* __restrict__ deg) {
    int e = blockIdx.x * 256 + threadIdx.x;
    if (e >= ET) return;
    int dst = (e < N_EDG) ? ei[N_EDG + e] : (e - N_EDG);
    atomicAdd(&deg[dst], 1);
}

__global__ __launch_bounds__(1024) void scan_offsets(const int* __restrict__ deg,
                                                     int* __restrict__ offs,
                                                     int* __restrict__ cur) {
    __shared__ int wsum[16];
    __shared__ int carry_s;
    int t = threadIdx.x;
    int wid = t >> 6, lane = t & 63;
    if (t == 0) { carry_s = 0; offs[0] = 0; }
    __syncthreads();
    for (int base = 0; base < N_NODES; base += 1024) {
        int i = base + t;
        int v = (i < N_NODES) ? deg[i] : 0;
        int sv = v;
        #pragma unroll
        for (int off = 1; off < 64; off <<= 1) {
            int n = __shfl_up(sv, off);
            if (lane >= off) sv += n;
        }
        if (lane == 63) wsum[wid] = sv;
        __syncthreads();
        int wpre = 0;
        #pragma unroll
        for (int w = 0; w < 16; ++w) wpre += (w < wid) ? wsum[w] : 0;
        int incl = sv + wpre + carry_s;
        if (i < N_NODES) {
            offs[i + 1] = incl;
            cur[i] = incl - v;
        }
        __syncthreads();
        if (t == 1023) carry_s = incl;
        __syncthreads();
    }
}

__global__ void fill_csr(const int* __restrict__ ei, int* __restrict__ cur,
                         int* __restrict__ esrc) {
    int e = blockIdx.x * 256 + threadIdx.x;
    if (e >= ET) return;
    int src, dst;
    if (e < N_EDG) { src = ei[e]; dst = ei[N_EDG + e]; }
    else { src = e - N_EDG; dst = src; }
    int pos = atomicAdd(&cur[dst], 1);
    esrc[pos] = src;
}

// ---------------- split fp32 -> bf16 hi/lo ----------------
__global__ __launch_bounds__(256) void split_x(const float* __restrict__ x,
        unsigned short* __restrict__ xh, unsigned short* __restrict__ xl) {
    int i = (blockIdx.x * 256 + threadIdx.x) * 4;
    if (i >= N_NODES * NFE) return;
    float4 v = *reinterpret_cast<const float4*>(x + i);
    ushort4 h, l;
    h.x = f2bf(v.x); l.x = f2bf(v.x - bf2f(h.x));
    h.y = f2bf(v.y); l.y = f2bf(v.y - bf2f(h.y));
    h.z = f2bf(v.z); l.z = f2bf(v.z - bf2f(h.z));
    h.w = f2bf(v.w); l.w = f2bf(v.w - bf2f(h.w));
    *reinterpret_cast<ushort4*>(xh + i) = h;
    *reinterpret_cast<ushort4*>(xl + i) = l;
}

// split + transpose W [256x512] -> Wt [512][256] (k contiguous), both matrices
__global__ __launch_bounds__(256) void split_w(const float* __restrict__ Wl,
        const float* __restrict__ Wr, unsigned short* __restrict__ Wth,
        unsigned short* __restrict__ Wtl) {
    const float* W = blockIdx.y ? Wr : Wl;
    unsigned short* oh = Wth + (size_t)blockIdx.y * (HD * NFE);
    unsigned short* ol = Wtl + (size_t)blockIdx.y * (HD * NFE);
    int i = blockIdx.x * 256 + threadIdx.x;
    if (i >= NFE * HD) return;
    int k = i >> 9, n = i & 511;
    float v = W[i];
    unsigned short h = f2bf(v), l = f2bf(v - bf2f(h));
    oh[n * NFE + k] = h;
    ol[n * NFE + k] = l;
}

// transpose W2 [512][16] -> Wt2 [2][16][512] (k contiguous per output col)
__global__ __launch_bounds__(256) void prep_w2(const float* __restrict__ Wl2,
        const float* __restrict__ Wr2, float* __restrict__ Wt2) {
    int i = blockIdx.x * 256 + threadIdx.x;   // 0..16383
    if (i >= 2 * NC * HD) return;
    int mat = i >> 13;
    int rem = i & 8191;
    int c = rem >> 9, k = rem & 511;
    const float* W = mat ? Wr2 : Wl2;
    Wt2[i] = W[k * NC + c];
}

// ---------------- GEMM1 via split-bf16 MFMA, fp16 output ----------------
#define ROWP 157
#define G1_NWG (8 * ROWP * 2)   // 2512; /8 = 314 exactly -> bijective swizzle
__global__ __launch_bounds__(256) void gemm1m(
        const unsigned short* __restrict__ xh, const unsigned short* __restrict__ xl,
        const unsigned short* __restrict__ Wth, const unsigned short* __restrict__ Wtl,
        const float* __restrict__ bl, const float* __restrict__ br,
        _Float16* __restrict__ outl, _Float16* __restrict__ outr) {
    __shared__ __align__(16) short Ah[2][128 * 32], Al[2][128 * 32];
    __shared__ __align__(16) short Bh[2][64 * 32],  Bls[2][64 * 32];

    int flat = blockIdx.x;
    int wgid = (flat & 7) * (G1_NWG / 8) + (flat >> 3);
    int z = wgid / (8 * ROWP);
    int rem = wgid - z * (8 * ROWP);
    int rowp = rem >> 3, colb = rem & 7;
    int row0 = rowp * 128, col0 = colb * 64;

    const unsigned short* Wh  = Wth + (size_t)z * (HD * NFE);
    const unsigned short* Wl_ = Wtl + (size_t)z * (HD * NFE);
    const float* bias = z ? br : bl;
    _Float16* out = z ? outr : outl;

    int tid = threadIdx.x;
    int w = tid >> 6, lane = tid & 63;
    int wr0 = (w >> 1) * 64, wn0 = (w & 1) * 32;
    int r16 = lane & 15, kb_l = lane >> 4;
    int rsub = lane >> 2, kch = lane & 3;

    f32x4 acc[4][2] = {};

    auto stage = [&](int buf, int k0) {
        #pragma unroll
        for (int i = 0; i < 2; ++i) {
            int inst = 2 * w + i;                 // 0..7
            int rl = inst * 16 + rsub;            // 0..127
            size_t goff = (size_t)(row0 + rl) * NFE + k0 + kch * 8;
            __builtin_amdgcn_global_load_lds((const AS1 void*)(xh + goff),
                                             (AS3 void*)(&Ah[buf][inst * 512]), 16, 0, 0);
            __builtin_amdgcn_global_load_lds((const AS1 void*)(xl + goff),
                                             (AS3 void*)(&Al[buf][inst * 512]), 16, 0, 0);
        }
        int cl = w * 16 + rsub;                   // 0..63
        size_t boff = (size_t)(col0 + cl) * NFE + k0 + kch * 8;
        __builtin_amdgcn_global_load_lds((const AS1 void*)(Wh + boff),
                                         (AS3 void*)(&Bh[buf][w * 512]), 16, 0, 0);
        __builtin_amdgcn_global_load_lds((const AS1 void*)(Wl_ + boff),
                                         (AS3 void*)(&Bls[buf][w * 512]), 16, 0, 0);
    };

    stage(0, 0);
    __syncthreads();

    for (int t = 0; t < 8; ++t) {
        int buf = t & 1;
        if (t < 7) stage(buf ^ 1, (t + 1) * 32);

        short8 ah[4], alv[4], bhv[2], blv[2];
        #pragma unroll
        for (int mi = 0; mi < 4; ++mi) {
            int idx = (wr0 + mi * 16 + r16) * 32 + kb_l * 8;
            ah[mi]  = *reinterpret_cast<const short8*>(&Ah[buf][idx]);
            alv[mi] = *reinterpret_cast<const short8*>(&Al[buf][idx]);
        }
        #pragma unroll
        for (int ni = 0; ni < 2; ++ni) {
            int idx = (wn0 + ni * 16 + r16) * 32 + kb_l * 8;
            bhv[ni] = *reinterpret_cast<const short8*>(&Bh[buf][idx]);
            blv[ni] = *reinterpret_cast<const short8*>(&Bls[buf][idx]);
        }
        #pragma unroll
        for (int mi = 0; mi < 4; ++mi)
            #pragma unroll
            for (int ni = 0; ni < 2; ++ni) {
                acc[mi][ni] = __builtin_amdgcn_mfma_f32_16x16x32_bf16(ah[mi],  bhv[ni], acc[mi][ni], 0, 0, 0);
                acc[mi][ni] = __builtin_amdgcn_mfma_f32_16x16x32_bf16(ah[mi],  blv[ni], acc[mi][ni], 0, 0, 0);
                acc[mi][ni] = __builtin_amdgcn_mfma_f32_16x16x32_bf16(alv[mi], bhv[ni], acc[mi][ni], 0, 0, 0);
            }
        __syncthreads();
    }

    int orow_base = row0 + wr0 + kb_l * 4;
    int ocol_base = col0 + wn0 + r16;
    #pragma unroll
    for (int mi = 0; mi < 4; ++mi)
        #pragma unroll
        for (int ni = 0; ni < 2; ++ni) {
            int col = ocol_base + ni * 16;
            float bv = bias[col];
            #pragma unroll
            for (int r = 0; r < 4; ++r) {
                int row = orow_base + mi * 16 + r;
                if (row < N_NODES)
                    out[(size_t)row * HD + col] = (_Float16)(acc[mi][ni][r] + bv);
            }
        }
}

// ---------------- fused layer1 + layer2-GEMM ----------------
// Per node-wave: online-softmax aggregate -> h in registers (8 dims/lane),
// then xl2/xr2 = h @ W2 + b2 via coalesced Wt2 loads + fold-reduce with
// STATIC part[] indices (lane-dependence expressed as value selects only;
// avoids scratch spill / cndmask index chains — rule #20).
__global__ __launch_bounds__(256) void fused1(const int* __restrict__ offs,
        const int* __restrict__ esrc,
        const _Float16* __restrict__ xl1, const _Float16* __restrict__ xr1,
        const float* __restrict__ att1, const float* __restrict__ bias1,
        const float* __restrict__ Wt2, const float* __restrict__ bl2,
        const float* __restrict__ br2,
        float* __restrict__ xl2, float* __restrict__ xr2) {
    int wid = (blockIdx.x * 256 + threadIdx.x) >> 6;
    int lane = threadIdx.x & 63;
    if (wid >= N_NODES) return;
    int beg = offs[wid], end = offs[wid + 1];

    float att[8], xr[8];
    *reinterpret_cast<float4*>(&att[0]) = *reinterpret_cast<const float4*>(att1 + lane * 8);
    *reinterpret_cast<float4*>(&att[4]) = *reinterpret_cast<const float4*>(att1 + lane * 8 + 4);
    {
        half8 hv = *reinterpret_cast<const half8*>(xr1 + (size_t)wid * HD + lane * 8);
        #pragma unroll
        for (int q = 0; q < 8; ++q) xr[q] = (float)hv[q];
    }

    float m = -3.4e38f, s = 0.f;
    float acc[8] = {};

    half8 xsp;
    xsp = *reinterpret_cast<const half8*>(xl1 + (size_t)esrc[beg] * HD + lane * 8);

    for (int j = beg; j < end; ++j) {
        half8 curh = xsp;
        if (j + 1 < end)
            xsp = *reinterpret_cast<const half8*>(xl1 + (size_t)esrc[j + 1] * HD + lane * 8);
        float cx[8];
        #pragma unroll
        for (int q = 0; q < 8; ++q) cx[q] = (float)curh[q];

        float v = 0.f;
        #pragma unroll
        for (int q = 0; q < 8; ++q) {
            float t = cx[q] + xr[q];
            t = t > 0.f ? t : 0.2f * t;
            v = fmaf(t, att[q], v);
        }
        v += __shfl_xor(v, 1);
        v += __shfl_xor(v, 2);
        v += __shfl_xor(v, 4);
        float nm = fmaxf(m, v);
        float sc = __expf(m - nm);
        float p  = __expf(v - nm);
        s = s * sc + p;
        #pragma unroll
        for (int q = 0; q < 8; ++q) acc[q] = fmaf(acc[q], sc, p * cx[q]);
        m = nm;
    }

    float inv = 1.0f / s;
    float h[8];
    #pragma unroll
    for (int q = 0; q < 8; ++q) {
        float bi = bias1[lane * 8 + q];
        h[q] = fmaxf(fmaf(acc[q], inv, bi), 0.f);   // h = relu(agg + bias1)
    }

    // ---- layer-2 linear: coalesced Wt2 + static-index fold-reduce ----
    float r01[2];
    #pragma unroll
    for (int mat = 0; mat < 2; ++mat) {
        const float* Wt = Wt2 + (size_t)mat * (NC * HD);
        float part[16];
        #pragma unroll
        for (int o = 0; o < 16; ++o) {
            const float* wp = Wt + o * HD + lane * 8;
            float4 w0 = *reinterpret_cast<const float4*>(wp);
            float4 w1 = *reinterpret_cast<const float4*>(wp + 4);
            float p0 = fmaf(h[0], w0.x, fmaf(h[1], w0.y, fmaf(h[2], w0.z, h[3] * w0.w)));
            float p1 = fmaf(h[4], w1.x, fmaf(h[5], w1.y, fmaf(h[6], w1.z, h[7] * w1.w)));
            part[o] = p0 + p1;
        }
        // fold over lane bits 5,4,3,2 — all part[] indices compile-time;
        // lane-dependence is value-selects only.
        #pragma unroll
        for (int stepi = 0; stepi < 4; ++stepi) {
            const int sh   = 32 >> stepi;   // 32,16,8,4
            const int half = 8 >> stepi;    // 8,4,2,1
            bool hi = (lane & sh) != 0;
            #pragma unroll
            for (int i = 0; i < half; ++i) {
                float keepv = hi ? part[i + half] : part[i];
                float shipv = hi ? part[i] : part[i + half];
                part[i] = keepv + __shfl_xor(shipv, sh);
            }
        }
        float r = part[0];
        r += __shfl_xor(r, 2);
        r += __shfl_xor(r, 1);
        r01[mat] = r;
    }
    int o = (lane >> 2) & 15;   // output col owned by this 4-lane group
    if ((lane & 3) == 0) xl2[(size_t)wid * NC + o] = r01[0] + bl2[o];
    if ((lane & 3) == 1) xr2[(size_t)wid * NC + o] = r01[1] + br2[o];
}

// ---------------- fused layer2 ----------------
__global__ __launch_bounds__(256) void fused2(const int* __restrict__ offs,
        const int* __restrict__ esrc,
        const float* __restrict__ xl2, const float* __restrict__ xr2,
        const float* __restrict__ att2, const float* __restrict__ bias2,
        float* __restrict__ out) {
    int wid = (blockIdx.x * 256 + threadIdx.x) >> 6;
    int lane = threadIdx.x & 63;
    if (wid >= N_NODES) return;
    int g = lane >> 4, d = lane & 15;
    int beg = offs[wid], end = offs[wid + 1];

    float xr = xr2[(size_t)wid * NC + d];
    float at = att2[d];
    float m = -3.4e38f, s = 0.f, acc = 0.f;

    for (int j = beg + g; j < end; j += 4) {
        int src = esrc[j];
        float xs = xl2[(size_t)src * NC + d];
        float t = xs + xr;
        t = t > 0.f ? t : 0.2f * t;
        float v = t * at;
        v += __shfl_xor(v, 1);
        v += __shfl_xor(v, 2);
        v += __shfl_xor(v, 4);
        v += __shfl_xor(v, 8);
        float nm = fmaxf(m, v);
        float sc = __expf(m - nm), p = __expf(v - nm);
        s = s * sc + p;
        acc = fmaf(acc, sc, p * xs);
        m = nm;
    }
    #pragma unroll
    for (int off = 16; off < 64; off <<= 1) {
        float om = __shfl_xor(m, off);
        float os = __shfl_xor(s, off);
        float oa = __shfl_xor(acc, off);
        float nm = fmaxf(m, om);
        float c1 = __expf(m - nm), c2 = __expf(om - nm);
        s = s * c1 + os * c2;
        acc = acc * c1 + oa * c2;
        m = nm;
    }
    if (lane < 16) out[(size_t)wid * NC + d] = acc / s + bias2[d];
}

// ---------------- launch ----------------
extern "C" void kernel_launch(void* const* d_in, const int* in_sizes, int n_in,
                              void* d_out, int out_size, void* d_ws, size_t ws_size,
                              hipStream_t stream) {
    const float* x     = (const float*)d_in[0];
    const int*   ei    = (const int*)d_in[1];
    const float* W_l1  = (const float*)d_in[2];
    const float* b_l1  = (const float*)d_in[3];
    const float* W_r1  = (const float*)d_in[4];
    const float* b_r1  = (const float*)d_in[5];
    const float* att1  = (const float*)d_in[6];
    const float* bias1 = (const float*)d_in[7];
    const float* W_l2  = (const float*)d_in[8];
    const float* b_l2  = (const float*)d_in[9];
    const float* W_r2  = (const float*)d_in[10];
    const float* b_r2  = (const float*)d_in[11];
    const float* att2  = (const float*)d_in[12];
    const float* bias2 = (const float*)d_in[13];
    float* out = (float*)d_out;

    char* ws = (char*)d_ws;
    _Float16* xl1 = (_Float16*)ws; ws += (size_t)N_NODES * HD * sizeof(_Float16);
    _Float16* xr1 = (_Float16*)ws; ws += (size_t)N_NODES * HD * sizeof(_Float16);
    float* xl2  = (float*)ws; ws += (size_t)N_NODES * NC * sizeof(float);
    float* xr2  = (float*)ws; ws += (size_t)N_NODES * NC * sizeof(float);
    float* Wt2  = (float*)ws; ws += (size_t)2 * NC * HD * sizeof(float);
    int* deg    = (int*)ws; ws += (size_t)N_NODES * sizeof(int);
    int* offs   = (int*)ws; ws += (size_t)(N_NODES + 1) * sizeof(int);
    int* cursor = (int*)ws; ws += (size_t)N_NODES * sizeof(int);
    int* esrc   = (int*)ws; ws += (size_t)ET * sizeof(int);
    unsigned short* xh  = (unsigned short*)ws; ws += (size_t)MPAD * NFE * sizeof(short);
    unsigned short* xlo = (unsigned short*)ws; ws += (size_t)MPAD * NFE * sizeof(short);
    unsigned short* Wth = (unsigned short*)ws; ws += (size_t)2 * HD * NFE * sizeof(short);
    unsigned short* Wtl = (unsigned short*)ws; ws += (size_t)2 * HD * NFE * sizeof(short);

    hipMemsetAsync(deg, 0, N_NODES * sizeof(int), stream);
    count_deg<<<(ET + 255) / 256, 256, 0, stream>>>(ei, deg);
    scan_offsets<<<1, 1024, 0, stream>>>(deg, offs, cursor);
    fill_csr<<<(ET + 255) / 256, 256, 0, stream>>>(ei, cursor, esrc);

    split_x<<<(N_NODES * NFE / 4 + 255) / 256, 256, 0, stream>>>(x, xh, xlo);
    split_w<<<dim3((NFE * HD + 255) / 256, 2), 256, 0, stream>>>(W_l1, W_r1, Wth, Wtl);
    prep_w2<<<(2 * NC * HD + 255) / 256, 256, 0, stream>>>(W_l2, W_r2, Wt2);

    gemm1m<<<G1_NWG, 256, 0, stream>>>(xh, xlo, Wth, Wtl, b_l1, b_r1, xl1, xr1);
    fused1<<<(N_NODES + 3) / 4, 256, 0, stream>>>(offs, esrc, xl1, xr1, att1, bias1,
                                                  Wt2, b_l2, b_r2, xl2, xr2);
    fused2<<<(N_NODES + 3) / 4, 256, 0, stream>>>(offs, esrc, xl2, xr2, att2, bias2, out);
}

// Round 12
// 366.663 us; speedup vs baseline: 1.0861x; 1.0861x over previous
//
#include <hip/hip_runtime.h>
#include <hip/hip_bf16.h>
#include <stdint.h>

#define N_NODES 20000
#define MPAD    20096               // 157 * 128 padded rows for MFMA panels
#define N_EDG   320000
#define ET      (N_EDG + N_NODES)   // 340000
#define NFE     256
#define HD      512
#define NH      8
#define DH      64
#define NC      16

typedef __attribute__((ext_vector_type(8))) short short8;
typedef __attribute__((ext_vector_type(8))) _Float16 half8;
typedef __attribute__((ext_vector_type(4))) float f32x4;

#define AS1 __attribute__((address_space(1)))
#define AS3 __attribute__((address_space(3)))

__device__ __forceinline__ unsigned short f2bf(float f) {
    unsigned u = __float_as_uint(f);
    return (unsigned short)((u + 0x7FFFu + ((u >> 16) & 1u)) >> 16);
}
__device__ __forceinline__ float bf2f(unsigned short s) {
    return __uint_as_float(((unsigned)s) << 16);
}

// ---------------- CSR build ----------------
__global__ void count_deg(const int* __restrict__ ei, int* __restrict__ deg) {
    int e = blockIdx.x * 256 + threadIdx.x;
    if (e >= ET) return;
    int dst = (e < N_EDG) ? ei[N_EDG + e] : (e - N_EDG);
    atomicAdd(&deg[dst], 1);
}

__global__ __launch_bounds__(1024) void scan_offsets(const int* __restrict__ deg,
                                                     int* __restrict__ offs,
                                                     int* __restrict__ cur) {
    __shared__ int wsum[16];
    __shared__ int carry_s;
    int t = threadIdx.x;
    int wid = t >> 6, lane = t & 63;
    if (t == 0) { carry_s = 0; offs[0] = 0; }
    __syncthreads();
    for (int base = 0; base < N_NODES; base += 1024) {
        int i = base + t;
        int v = (i < N_NODES) ? deg[i] : 0;
        int sv = v;
        #pragma unroll
        for (int off = 1; off < 64; off <<= 1) {
            int n = __shfl_up(sv, off);
            if (lane >= off) sv += n;
        }
        if (lane == 63) wsum[wid] = sv;
        __syncthreads();
        int wpre = 0;
        #pragma unroll
        for (int w = 0; w < 16; ++w) wpre += (w < wid) ? wsum[w] : 0;
        int incl = sv + wpre + carry_s;
        if (i < N_NODES) {
            offs[i + 1] = incl;
            cur[i] = incl - v;
        }
        __syncthreads();
        if (t == 1023) carry_s = incl;
        __syncthreads();
    }
}

__global__ void fill_csr(const int* __restrict__ ei, int* __restrict__ cur,
                         int* __restrict__ esrc) {
    int e = blockIdx.x * 256 + threadIdx.x;
    if (e >= ET) return;
    int src, dst;
    if (e < N_EDG) { src = ei[e]; dst = ei[N_EDG + e]; }
    else { src = e - N_EDG; dst = src; }
    int pos = atomicAdd(&cur[dst], 1);
    esrc[pos] = src;
}

// ---------------- split fp32 -> bf16 hi/lo ----------------
__global__ __launch_bounds__(256) void split_x(const float* __restrict__ x,
        unsigned short* __restrict__ xh, unsigned short* __restrict__ xl) {
    int i = (blockIdx.x * 256 + threadIdx.x) * 4;
    if (i >= N_NODES * NFE) return;
    float4 v = *reinterpret_cast<const float4*>(x + i);
    ushort4 h, l;
    h.x = f2bf(v.x); l.x = f2bf(v.x - bf2f(h.x));
    h.y = f2bf(v.y); l.y = f2bf(v.y - bf2f(h.y));
    h.z = f2bf(v.z); l.z = f2bf(v.z - bf2f(h.z));
    h.w = f2bf(v.w); l.w = f2bf(v.w - bf2f(h.w));
    *reinterpret_cast<ushort4*>(xh + i) = h;
    *reinterpret_cast<ushort4*>(xl + i) = l;
}

// split + transpose W [256x512] -> Wt [512][256] (k contiguous), both matrices
__global__ __launch_bounds__(256) void split_w(const float* __restrict__ Wl,
        const float* __restrict__ Wr, unsigned short* __restrict__ Wth,
        unsigned short* __restrict__ Wtl) {
    const float* W = blockIdx.y ? Wr : Wl;
    unsigned short* oh = Wth + (size_t)blockIdx.y * (HD * NFE);
    unsigned short* ol = Wtl + (size_t)blockIdx.y * (HD * NFE);
    int i = blockIdx.x * 256 + threadIdx.x;
    if (i >= NFE * HD) return;
    int k = i >> 9, n = i & 511;
    float v = W[i];
    unsigned short h = f2bf(v), l = f2bf(v - bf2f(h));
    oh[n * NFE + k] = h;
    ol[n * NFE + k] = l;
}

// ---------------- GEMM1 via split-bf16 MFMA, fp16 output ----------------
#define ROWP 157
#define G1_NWG (8 * ROWP * 2)   // 2512; /8 = 314 exactly -> bijective swizzle
__global__ __launch_bounds__(256) void gemm1m(
        const unsigned short* __restrict__ xh, const unsigned short* __restrict__ xl,
        const unsigned short* __restrict__ Wth, const unsigned short* __restrict__ Wtl,
        const float* __restrict__ bl, const float* __restrict__ br,
        _Float16* __restrict__ outl, _Float16* __restrict__ outr) {
    __shared__ __align__(16) short Ah[2][128 * 32], Al[2][128 * 32];
    __shared__ __align__(16) short Bh[2][64 * 32],  Bls[2][64 * 32];

    int flat = blockIdx.x;
    int wgid = (flat & 7) * (G1_NWG / 8) + (flat >> 3);
    int z = wgid / (8 * ROWP);
    int rem = wgid - z * (8 * ROWP);
    int rowp = rem >> 3, colb = rem & 7;
    int row0 = rowp * 128, col0 = colb * 64;

    const unsigned short* Wh  = Wth + (size_t)z * (HD * NFE);
    const unsigned short* Wl_ = Wtl + (size_t)z * (HD * NFE);
    const float* bias = z ? br : bl;
    _Float16* out = z ? outr : outl;

    int tid = threadIdx.x;
    int w = tid >> 6, lane = tid & 63;
    int wr0 = (w >> 1) * 64, wn0 = (w & 1) * 32;
    int r16 = lane & 15, kb_l = lane >> 4;
    int rsub = lane >> 2, kch = lane & 3;

    f32x4 acc[4][2] = {};

    auto stage = [&](int buf, int k0) {
        #pragma unroll
        for (int i = 0; i < 2; ++i) {
            int inst = 2 * w + i;                 // 0..7
            int rl = inst * 16 + rsub;            // 0..127
            size_t goff = (size_t)(row0 + rl) * NFE + k0 + kch * 8;
            __builtin_amdgcn_global_load_lds((const AS1 void*)(xh + goff),
                                             (AS3 void*)(&Ah[buf][inst * 512]), 16, 0, 0);
            __builtin_amdgcn_global_load_lds((const AS1 void*)(xl + goff),
                                             (AS3 void*)(&Al[buf][inst * 512]), 16, 0, 0);
        }
        int cl = w * 16 + rsub;                   // 0..63
        size_t boff = (size_t)(col0 + cl) * NFE + k0 + kch * 8;
        __builtin_amdgcn_global_load_lds((const AS1 void*)(Wh + boff),
                                         (AS3 void*)(&Bh[buf][w * 512]), 16, 0, 0);
        __builtin_amdgcn_global_load_lds((const AS1 void*)(Wl_ + boff),
                                         (AS3 void*)(&Bls[buf][w * 512]), 16, 0, 0);
    };

    stage(0, 0);
    __syncthreads();

    for (int t = 0; t < 8; ++t) {
        int buf = t & 1;
        if (t < 7) stage(buf ^ 1, (t + 1) * 32);

        short8 ah[4], alv[4], bhv[2], blv[2];
        #pragma unroll
        for (int mi = 0; mi < 4; ++mi) {
            int idx = (wr0 + mi * 16 + r16) * 32 + kb_l * 8;
            ah[mi]  = *reinterpret_cast<const short8*>(&Ah[buf][idx]);
            alv[mi] = *reinterpret_cast<const short8*>(&Al[buf][idx]);
        }
        #pragma unroll
        for (int ni = 0; ni < 2; ++ni) {
            int idx = (wn0 + ni * 16 + r16) * 32 + kb_l * 8;
            bhv[ni] = *reinterpret_cast<const short8*>(&Bh[buf][idx]);
            blv[ni] = *reinterpret_cast<const short8*>(&Bls[buf][idx]);
        }
        #pragma unroll
        for (int mi = 0; mi < 4; ++mi)
            #pragma unroll
            for (int ni = 0; ni < 2; ++ni) {
                acc[mi][ni] = __builtin_amdgcn_mfma_f32_16x16x32_bf16(ah[mi],  bhv[ni], acc[mi][ni], 0, 0, 0);
                acc[mi][ni] = __builtin_amdgcn_mfma_f32_16x16x32_bf16(ah[mi],  blv[ni], acc[mi][ni], 0, 0, 0);
                acc[mi][ni] = __builtin_amdgcn_mfma_f32_16x16x32_bf16(alv[mi], bhv[ni], acc[mi][ni], 0, 0, 0);
            }
        __syncthreads();
    }

    int orow_base = row0 + wr0 + kb_l * 4;
    int ocol_base = col0 + wn0 + r16;
    #pragma unroll
    for (int mi = 0; mi < 4; ++mi)
        #pragma unroll
        for (int ni = 0; ni < 2; ++ni) {
            int col = ocol_base + ni * 16;
            float bv = bias[col];
            #pragma unroll
            for (int r = 0; r < 4; ++r) {
                int row = orow_base + mi * 16 + r;
                if (row < N_NODES)
                    out[(size_t)row * HD + col] = (_Float16)(acc[mi][ni][r] + bv);
            }
        }
}

// ---------------- fused layer1: fp16 gather, fp32 compute (round-6 form) ----
__global__ __launch_bounds__(256) void fused1(const int* __restrict__ offs,
        const int* __restrict__ esrc,
        const _Float16* __restrict__ xl1, const _Float16* __restrict__ xr1,
        const float* __restrict__ att1, const float* __restrict__ bias1,
        float* __restrict__ hout) {
    int wid = (blockIdx.x * 256 + threadIdx.x) >> 6;
    int lane = threadIdx.x & 63;
    if (wid >= N_NODES) return;
    int beg = offs[wid], end = offs[wid + 1];

    float att[8], xr[8];
    *reinterpret_cast<float4*>(&att[0]) = *reinterpret_cast<const float4*>(att1 + lane * 8);
    *reinterpret_cast<float4*>(&att[4]) = *reinterpret_cast<const float4*>(att1 + lane * 8 + 4);
    {
        half8 hv = *reinterpret_cast<const half8*>(xr1 + (size_t)wid * HD + lane * 8);
        #pragma unroll
        for (int q = 0; q < 8; ++q) xr[q] = (float)hv[q];
    }

    float m = -3.4e38f, s = 0.f;
    float acc[8] = {};

    half8 xsp;
    xsp = *reinterpret_cast<const half8*>(xl1 + (size_t)esrc[beg] * HD + lane * 8);

    for (int j = beg; j < end; ++j) {
        half8 curh = xsp;
        if (j + 1 < end)
            xsp = *reinterpret_cast<const half8*>(xl1 + (size_t)esrc[j + 1] * HD + lane * 8);
        float cx[8];
        #pragma unroll
        for (int q = 0; q < 8; ++q) cx[q] = (float)curh[q];

        float v = 0.f;
        #pragma unroll
        for (int q = 0; q < 8; ++q) {
            float t = cx[q] + xr[q];
            t = t > 0.f ? t : 0.2f * t;
            v = fmaf(t, att[q], v);
        }
        v += __shfl_xor(v, 1);
        v += __shfl_xor(v, 2);
        v += __shfl_xor(v, 4);
        float nm = fmaxf(m, v);
        float sc = __expf(m - nm);
        float p  = __expf(v - nm);
        s = s * sc + p;
        #pragma unroll
        for (int q = 0; q < 8; ++q) acc[q] = fmaf(acc[q], sc, p * cx[q]);
        m = nm;
    }

    float inv = 1.0f / s;
    float o[8];
    #pragma unroll
    for (int q = 0; q < 8; ++q) {
        float bi = bias1[lane * 8 + q];
        o[q] = fmaxf(fmaf(acc[q], inv, bi), 0.f);
    }
    float* op = hout + (size_t)wid * HD + lane * 8;
    *reinterpret_cast<float4*>(op)     = *reinterpret_cast<float4*>(&o[0]);
    *reinterpret_cast<float4*>(op + 4) = *reinterpret_cast<float4*>(&o[4]);
}

// ---------------- GEMM2: [20000x512] @ [512x16] x2, 8-way ILP ----------------
__global__ __launch_bounds__(256) void gemm2(const float* __restrict__ h,
        const float* __restrict__ Wl2, const float* __restrict__ bl2,
        const float* __restrict__ Wr2, const float* __restrict__ br2,
        float* __restrict__ xl2, float* __restrict__ xr2) {
    int tx = threadIdx.x & 31;
    int ty = threadIdx.x >> 5;
    int row = blockIdx.x * 8 + ty;
    if (row >= N_NODES) return;
    const float* W = (tx < 16) ? Wl2 : Wr2;
    int c = tx & 15;
    const float4* hr4 = reinterpret_cast<const float4*>(h + (size_t)row * HD);
    // 8 independent accumulator chains (fp32 can't be reassociated by compiler)
    float a0 = 0.f, a1 = 0.f, a2 = 0.f, a3 = 0.f;
    float a4 = 0.f, a5 = 0.f, a6 = 0.f, a7 = 0.f;
    #pragma unroll 8
    for (int k8 = 0; k8 < HD / 8; ++k8) {
        float4 v0 = hr4[k8 * 2];
        float4 v1 = hr4[k8 * 2 + 1];
        int k = k8 * 8;
        a0 = fmaf(v0.x, W[(k + 0) * NC + c], a0);
        a1 = fmaf(v0.y, W[(k + 1) * NC + c], a1);
        a2 = fmaf(v0.z, W[(k + 2) * NC + c], a2);
        a3 = fmaf(v0.w, W[(k + 3) * NC + c], a3);
        a4 = fmaf(v1.x, W[(k + 4) * NC + c], a4);
        a5 = fmaf(v1.y, W[(k + 5) * NC + c], a5);
        a6 = fmaf(v1.z, W[(k + 6) * NC + c], a6);
        a7 = fmaf(v1.w, W[(k + 7) * NC + c], a7);
    }
    float acc = ((a0 + a1) + (a2 + a3)) + ((a4 + a5) + (a6 + a7));
    if (tx < 16) xl2[(size_t)row * NC + c] = acc + bl2[c];
    else         xr2[(size_t)row * NC + c] = acc + br2[c];
}

// ---------------- fused layer2 ----------------
__global__ __launch_bounds__(256) void fused2(const int* __restrict__ offs,
        const int* __restrict__ esrc,
        const float* __restrict__ xl2, const float* __restrict__ xr2,
        const float* __restrict__ att2, const float* __restrict__ bias2,
        float* __restrict__ out) {
    int wid = (blockIdx.x * 256 + threadIdx.x) >> 6;
    int lane = threadIdx.x & 63;
    if (wid >= N_NODES) return;
    int g = lane >> 4, d = lane & 15;
    int beg = offs[wid], end = offs[wid + 1];

    float xr = xr2[(size_t)wid * NC + d];
    float at = att2[d];
    float m = -3.4e38f, s = 0.f, acc = 0.f;

    for (int j = beg + g; j < end; j += 4) {
        int src = esrc[j];
        float xs = xl2[(size_t)src * NC + d];
        float t = xs + xr;
        t = t > 0.f ? t : 0.2f * t;
        float v = t * at;
        v += __shfl_xor(v, 1);
        v += __shfl_xor(v, 2);
        v += __shfl_xor(v, 4);
        v += __shfl_xor(v, 8);
        float nm = fmaxf(m, v);
        float sc = __expf(m - nm), p = __expf(v - nm);
        s = s * sc + p;
        acc = fmaf(acc, sc, p * xs);
        m = nm;
    }
    #pragma unroll
    for (int off = 16; off < 64; off <<= 1) {
        float om = __shfl_xor(m, off);
        float os = __shfl_xor(s, off);
        float oa = __shfl_xor(acc, off);
        float nm = fmaxf(m, om);
        float c1 = __expf(m - nm), c2 = __expf(om - nm);
        s = s * c1 + os * c2;
        acc = acc * c1 + oa * c2;
        m = nm;
    }
    if (lane < 16) out[(size_t)wid * NC + d] = acc / s + bias2[d];
}

// ---------------- launch ----------------
extern "C" void kernel_launch(void* const* d_in, const int* in_sizes, int n_in,
                              void* d_out, int out_size, void* d_ws, size_t ws_size,
                              hipStream_t stream) {
    const float* x     = (const float*)d_in[0];
    const int*   ei    = (const int*)d_in[1];
    const float* W_l1  = (const float*)d_in[2];
    const float* b_l1  = (const float*)d_in[3];
    const float* W_r1  = (const float*)d_in[4];
    const float* b_r1  = (const float*)d_in[5];
    const float* att1  = (const float*)d_in[6];
    const float* bias1 = (const float*)d_in[7];
    const float* W_l2  = (const float*)d_in[8];
    const float* b_l2  = (const float*)d_in[9];
    const float* W_r2  = (const float*)d_in[10];
    const float* b_r2  = (const float*)d_in[11];
    const float* att2  = (const float*)d_in[12];
    const float* bias2 = (const float*)d_in[13];
    float* out = (float*)d_out;

    char* ws = (char*)d_ws;
    _Float16* xl1 = (_Float16*)ws; ws += (size_t)N_NODES * HD * sizeof(_Float16);
    _Float16* xr1 = (_Float16*)ws; ws += (size_t)N_NODES * HD * sizeof(_Float16);
    float* hbuf = (float*)ws; ws += (size_t)N_NODES * HD * sizeof(float);
    float* xl2  = (float*)ws; ws += (size_t)N_NODES * NC * sizeof(float);
    float* xr2  = (float*)ws; ws += (size_t)N_NODES * NC * sizeof(float);
    int* deg    = (int*)ws; ws += (size_t)N_NODES * sizeof(int);
    int* offs   = (int*)ws; ws += (size_t)(N_NODES + 1) * sizeof(int);
    int* cursor = (int*)ws; ws += (size_t)N_NODES * sizeof(int);
    int* esrc   = (int*)ws; ws += (size_t)ET * sizeof(int);
    unsigned short* xh  = (unsigned short*)ws; ws += (size_t)MPAD * NFE * sizeof(short);
    unsigned short* xlo = (unsigned short*)ws; ws += (size_t)MPAD * NFE * sizeof(short);
    unsigned short* Wth = (unsigned short*)ws; ws += (size_t)2 * HD * NFE * sizeof(short);
    unsigned short* Wtl = (unsigned short*)ws; ws += (size_t)2 * HD * NFE * sizeof(short);

    hipMemsetAsync(deg, 0, N_NODES * sizeof(int), stream);
    count_deg<<<(ET + 255) / 256, 256, 0, stream>>>(ei, deg);
    scan_offsets<<<1, 1024, 0, stream>>>(deg, offs, cursor);
    fill_csr<<<(ET + 255) / 256, 256, 0, stream>>>(ei, cursor, esrc);

    split_x<<<(N_NODES * NFE / 4 + 255) / 256, 256, 0, stream>>>(x, xh, xlo);
    split_w<<<dim3((NFE * HD + 255) / 256, 2), 256, 0, stream>>>(W_l1, W_r1, Wth, Wtl);

    gemm1m<<<G1_NWG, 256, 0, stream>>>(xh, xlo, Wth, Wtl, b_l1, b_r1, xl1, xr1);
    fused1<<<(N_NODES + 3) / 4, 256, 0, stream>>>(offs, esrc, xl1, xr1, att1, bias1, hbuf);

    gemm2<<<(N_NODES + 7) / 8, 256, 0, stream>>>(hbuf, W_l2, b_l2, W_r2, b_r2, xl2, xr2);
    fused2<<<(N_NODES + 3) / 4, 256, 0, stream>>>(offs, esrc, xl2, xr2, att2, bias2, out);
}